// Round 10
// baseline (204.495 us; speedup 1.0000x reference)
//
#include <hip/hip_runtime.h>
#include <hip/hip_fp16.h>
#include <math.h>

#define N_ANGLES 720
#define N_DET    725
#define N_SAMP   768
#define IMG_H    512
#define IMG_W    512

// Zero-border fp16 column-pair quad pack, shift S=4 (grid 520x520).
// Cell (jy,jx) holds corners of (fy,fx)=(jy-4,jx-4), packed h[0]=(v00,v10),
// h[1]=(v01,v11). Content cells: j in [3,515]; cells outside are zero.
// Sampling clamps coords to [0,519]; out-of-content samples contribute 0.
#define QW       520
#define QROWB    4160u                   // QW * 8 bytes per row
#define Q4BYTES  ((size_t)QW * QW * sizeof(uint2))

// zones (retuned R10): A near-axis theta<=11.25deg only — the 64-det-lane
// mapping is only line-efficient when rows/gather = 1+64*sin(theta) is small
// and union waste 64*tan(theta) is small. B1 8dx8t patches take everything
// up to 67.25deg; B2 16tx4d for near-90.
#define A_BLOCKS  (91 * 3)               // a in [0,45] U [675,719]
#define B1_ANG    448                    // a in [46,269] U [451,674]
#define B1_DBLK   23                     // 23 tiles of 32 detectors
#define B1_BLOCKS (B1_ANG * B1_DBLK)
#define B2_ANG    181                    // a in [270,450]
#define B2_DBLK   46                     // 46 tiles of 16 detectors
#define B2_BLOCKS (B2_ANG * B2_DBLK)

typedef _Float16 f16x2 __attribute__((ext_vector_type(2)));

__device__ __forceinline__ f16x2 pkrtz(float a, float b) {
    auto t = __builtin_amdgcn_cvt_pkrtz(a, b);
    union { decltype(t) s; f16x2 d; } u;
    u.s = t;
    return u.d;
}

__device__ __forceinline__ float fdot2f(f16x2 a, f16x2 b, float c) {
    using hraw = decltype(__builtin_amdgcn_cvt_pkrtz(0.0f, 0.0f));
    union { f16x2 s; hraw d; } ua, ub;
    ua.s = a;
    ub.s = b;
    return __builtin_amdgcn_fdot2(ua.d, ub.d, c, false);
}

__device__ __forceinline__ float img_at(const float* __restrict__ x,
                                        const float* __restrict__ r,
                                        int py, int px) {
    if ((unsigned)py < IMG_H && (unsigned)px < IMG_W) {
        int i = py * IMG_W + px;
        return x[i] + r[i];
    }
    return 0.0f;
}

// build Q (4 cells per thread, vectorized stores) + fused passthrough copy
__global__ __launch_bounds__(256) void build_q6(const float* __restrict__ x,
                                                const float* __restrict__ r,
                                                uint2* __restrict__ Q,
                                                float* __restrict__ out2) {
    int t = blockIdx.x * 256 + threadIdx.x;
    if (t < (IMG_H * IMG_W / 4))                       // passthrough, float4
        ((float4*)out2)[t] = ((const float4*)r)[t];
    int cell = t * 4;                                  // QW%4==0: same row
    if (cell >= QW * QW) return;
    int jy  = cell / QW;
    int jx0 = cell - jy * QW;
    int fy  = jy - 4;
    float row0[5], row1[5];
    #pragma unroll
    for (int e = 0; e < 5; ++e) {
        row0[e] = img_at(x, r, fy,     jx0 - 4 + e);
        row1[e] = img_at(x, r, fy + 1, jx0 - 4 + e);
    }
    uint2 o[4];
    #pragma unroll
    for (int e = 0; e < 4; ++e) {
        union { uint2 u; __half2 h2[2]; } q;
        q.h2[0] = __floats2half2_rn(row0[e],     row1[e]);     // (v00,v10)
        q.h2[1] = __floats2half2_rn(row0[e + 1], row1[e + 1]); // (v01,v11)
        o[e] = q.u;
    }
    *(uint4*)(&Q[cell])     = *(uint4*)(&o[0]);
    *(uint4*)(&Q[cell + 2]) = *(uint4*)(&o[2]);
}

// clamped packed-fp16 bilinear sample + accumulate; unsigned byte offsets
__device__ __forceinline__ float samp6(const char* __restrict__ Qb,
                                       float xs, float ys, float acc) {
    xs = fminf(fmaxf(xs, 0.0f), 519.0f);              // v_med3_f32
    ys = fminf(fmaxf(ys, 0.0f), 519.0f);
    unsigned jx = (unsigned)xs;
    unsigned jy = (unsigned)ys;
    float wx = __builtin_amdgcn_fractf(xs);
    float wy = __builtin_amdgcn_fractf(ys);
    unsigned offs = jy * QROWB + (jx << 3);           // 32-bit byte offset
    union { uint2 u; f16x2 h[2]; } q;
    q.u = *(const uint2*)(Qb + offs);
    f16x2 wx2 = pkrtz(wx, wx);
    f16x2 tb  = (q.h[1] - q.h[0]) * wx2 + q.h[0];     // (top,bot) packed lerp
    f16x2 w2  = pkrtz(1.0f - wy, wy);
    return fdot2f(tb, w2, acc);
}

// Clip ray (X0 - i*sn, Y0 + i*c), i in [0,767], to content box (3,516)^2.
// Completeness hint only; clamped zero-border sampling makes overruns free.
__device__ __forceinline__ void clip4(float X0, float Y0, float sn, float c,
                                      int& i0, int& i1) {
    float ilo = 0.0f, ihi = (float)(N_SAMP - 1);
    if (fabsf(sn) > 1e-6f) {
        float rr = -1.0f / sn;
        float a1 = (3.0f   - X0) * rr;
        float a2 = (516.0f - X0) * rr;
        ilo = fmaxf(ilo, fminf(a1, a2));
        ihi = fminf(ihi, fmaxf(a1, a2));
    } else if (X0 <= 3.0f || X0 >= 516.0f) {
        ihi = -1.0f;
    }
    if (fabsf(c) > 1e-6f) {
        float rr = 1.0f / c;
        float a1 = (3.0f   - Y0) * rr;
        float a2 = (516.0f - Y0) * rr;
        ilo = fmaxf(ilo, fminf(a1, a2));
        ihi = fminf(ihi, fmaxf(a1, a2));
    } else if (Y0 <= 3.0f || Y0 >= 516.0f) {
        ihi = -1.0f;
    }
    i0 = max(0, (int)ilo - 1);
    i1 = min(N_SAMP - 1, (int)ihi + 1);
}

__global__ __launch_bounds__(256) void project_f8(const uint2* __restrict__ Q,
                                                  float* __restrict__ sino) {
    const char* __restrict__ Qb = (const char*)Q;
    const int bid = blockIdx.x;

    if (bid < A_BLOCKS) {
        // ------------- A: one thread per (angle, detector), 64-det waves ----
        const int a_idx = bid / 3;
        const int a  = (a_idx <= 45) ? a_idx : a_idx + 629;  // [0,45] U [675,719]
        const int dt = (bid % 3) * 256 + threadIdx.x;
        const int d  = min(dt, N_DET - 1);

        const float th = (float)((double)a * (M_PI / 720.0));
        const float c  = cosf(th);
        const float sn = sinf(th);
        const float s  = (float)d - 362.0f;
        const float X0 = fmaf(s, c, 259.5f) + 383.5f * sn;
        const float Y0 = fmaf(s, sn, 259.5f) - 383.5f * c;

        int i0, i1;
        clip4(X0, Y0, sn, c, i0, i1);
        #pragma unroll
        for (int m = 1; m <= 32; m <<= 1) {
            i0 = min(i0, __shfl_xor(i0, m, 64));
            i1 = max(i1, __shfl_xor(i1, m, 64));
        }
        const int trips = __builtin_amdgcn_readfirstlane(i1 - i0 + 1);

        float acc = 0.0f;
        float xs = fmaf((float)i0, -sn, X0);
        float ys = fmaf((float)i0,  c,  Y0);
        #pragma unroll 4
        for (int k = 0; k < trips; ++k) {            // incremental stepping
            acc = samp6(Qb, xs, ys, acc);
            xs -= sn;
            ys += c;
        }
        if (dt < N_DET) sino[a * N_DET + dt] = acc;
    } else if (bid < A_BLOCKS + B1_BLOCKS) {
        // ------------- B1: wave = 8 det x 8 t patch (11.5..67.25 deg) -------
        const int idx  = bid - A_BLOCKS;
        const int ang  = idx / B1_DBLK;
        const int a    = (ang < 224) ? (46 + ang) : (451 + (ang - 224));
        const int dblk = idx - ang * B1_DBLK;
        const int lane = threadIdx.x & 63;
        const int dl   = lane & 7;
        const int tl   = lane >> 3;
        const int wv   = threadIdx.x >> 6;
        const int dt   = dblk * 32 + wv * 8 + dl;
        const int d    = min(dt, N_DET - 1);

        const float th = (float)((double)a * (M_PI / 720.0));
        const float c  = cosf(th);
        const float sn = sinf(th);
        const float s  = (float)d - 362.0f;
        const float X0 = fmaf(s, c, 259.5f) + 383.5f * sn;
        const float Y0 = fmaf(s, sn, 259.5f) - 383.5f * c;

        int i0, i1;
        clip4(X0, Y0, sn, c, i0, i1);
        #pragma unroll
        for (int m = 1; m <= 32; m <<= 1) {          // union over whole wave
            i0 = min(i0, __shfl_xor(i0, m, 64));
            i1 = max(i1, __shfl_xor(i1, m, 64));
        }
        const int trips = __builtin_amdgcn_readfirstlane((i1 - i0 + 8) >> 3);

        const float dx8 = -8.0f * sn, dy8 = 8.0f * c;
        float acc = 0.0f;
        float xs = fmaf((float)(i0 + tl), -sn, X0);
        float ys = fmaf((float)(i0 + tl),  c,  Y0);
        #pragma unroll 2
        for (int k = 0; k < trips; ++k) {
            acc = samp6(Qb, xs, ys, acc);
            xs += dx8;
            ys += dy8;
        }

        acc += __shfl_xor(acc, 8, 64);               // reduce over tl bits
        acc += __shfl_xor(acc, 16, 64);
        acc += __shfl_xor(acc, 32, 64);
        if (tl == 0 && dt < N_DET) sino[a * N_DET + dt] = acc;
    } else {
        // ------------- B2: near-90, wave = 16 t-lanes x 4 detectors ---------
        const int idx  = bid - A_BLOCKS - B1_BLOCKS;
        const int a    = 270 + idx / B2_DBLK;        // [270,450]
        const int dblk = idx % B2_DBLK;
        const int lane = threadIdx.x & 63;
        const int tl   = lane & 15;
        const int grp  = lane >> 4;
        const int wv   = threadIdx.x >> 6;
        const int d    = dblk * 16 + wv * 4 + grp;

        const float th = (float)((double)a * (M_PI / 720.0));
        const float c  = cosf(th);
        const float sn = sinf(th);
        const float s  = (float)d - 362.0f;
        const float X0 = fmaf(s, c, 259.5f) + 383.5f * sn;
        const float Y0 = fmaf(s, sn, 259.5f) - 383.5f * c;

        int i0, i1;
        clip4(X0, Y0, sn, c, i0, i1);
        i0 = min(i0, __shfl_xor(i0, 16, 64));
        i0 = min(i0, __shfl_xor(i0, 32, 64));
        i1 = max(i1, __shfl_xor(i1, 16, 64));
        i1 = max(i1, __shfl_xor(i1, 32, 64));
        const int trips = __builtin_amdgcn_readfirstlane((i1 - i0 + 16) >> 4);

        const float dx16 = -16.0f * sn, dy16 = 16.0f * c;
        float acc = 0.0f;
        float xs = fmaf((float)(i0 + tl), -sn, X0);
        float ys = fmaf((float)(i0 + tl),  c,  Y0);
        #pragma unroll 2
        for (int k = 0; k < trips; ++k) {
            acc = samp6(Qb, xs, ys, acc);
            xs += dx16;
            ys += dy16;
        }

        acc += __shfl_xor(acc, 1, 64);
        acc += __shfl_xor(acc, 2, 64);
        acc += __shfl_xor(acc, 4, 64);
        acc += __shfl_xor(acc, 8, 64);
        if (tl == 0 && d < N_DET) sino[a * N_DET + d] = acc;
    }
}

// ---------------- launcher ---------------------------------------------------
extern "C" void kernel_launch(void* const* d_in, const int* in_sizes, int n_in,
                              void* d_out, int out_size, void* d_ws, size_t ws_size,
                              hipStream_t stream) {
    const float* x    = (const float*)d_in[0];
    const float* reco = (const float*)d_in[1];
    float* out = (float*)d_out;

    if (ws_size >= Q4BYTES) {     // proven: ws held 2.16 MB in R4-R9 runs
        uint2* Q = (uint2*)d_ws;
        build_q6<<<(QW * QW / 4 + 255) / 256, 256, 0, stream>>>(x, reco, Q,
                                                            out + N_ANGLES * N_DET);
        project_f8<<<A_BLOCKS + B1_BLOCKS + B2_BLOCKS, 256, 0, stream>>>(Q, out);
    }
}